// Round 1
// baseline (284.837 us; speedup 1.0000x reference)
//
#include <hip/hip_runtime.h>

#define N_ATOMS 65536
#define N_SPECIES 4
#define N_MOL 512
#define ATOMS_PER_SPECIES (N_ATOMS / N_SPECIES)

typedef __attribute__((ext_vector_type(8))) __bf16 bf16x8;
typedef __attribute__((ext_vector_type(4))) float f32x4;

__device__ __forceinline__ unsigned short f2bf(float f) {
    unsigned int u = __float_as_uint(f);
    unsigned int r = (u + 0x7fffu + ((u >> 16) & 1u)) >> 16;
    return (unsigned short)r;
}

__device__ __forceinline__ float silu(float v) {
    return v / (1.0f + __expf(-v));
}

// ws layout (shorts): W1ps[4*512*256] | W2ps[4*256*256] | W1mp[4*256*256] | W2mp[4*256*256]
// then (floats, at byte 2621440): gW1ps[1024] bW1ps[1024] gW1mp[1024] bW1mp[1024]
#define WS_W1PS 0
#define WS_W2PS 524288
#define WS_W1MP 786432
#define WS_W2MP 1048576
#define WS_GB_BYTES 2621440

// Transpose + bf16-convert + XOR-swizzle weights into ws.
// Chunk image: [256 n][64 k] bf16, elem = (n*64+kl) ^ ((n&7)<<3)  (matches LDS read swizzle)
__global__ __launch_bounds__(256) void prep_w(const float* __restrict__ Wps1,
                                              const float* __restrict__ Wps2,
                                              const float* __restrict__ Wmp1,
                                              const float* __restrict__ Wmp2,
                                              short* __restrict__ wdst) {
    __shared__ short Ts[16384];
    int b = blockIdx.x;
    const float* src; int K; long dstbase; int s, c;
    if (b < 32)      { src = Wps1; K = 512; s = b >> 3;        c = b & 7;        dstbase = WS_W1PS; }
    else if (b < 48) { src = Wps2; K = 256; s = (b - 32) >> 2; c = (b - 32) & 3; dstbase = WS_W2PS; }
    else if (b < 64) { src = Wmp1; K = 256; s = (b - 48) >> 2; c = (b - 48) & 3; dstbase = WS_W1MP; }
    else             { src = Wmp2; K = 256; s = (b - 64) >> 2; c = (b - 64) & 3; dstbase = WS_W2MP; }
    int n = threadIdx.x;   // 0..255
    const float* sp = src + (long)s * K * 256 + (long)c * 64 * 256 + n;
    #pragma unroll 4
    for (int kl = 0; kl < 64; ++kl) {
        float v = sp[(long)kl * 256];
        Ts[(n * 64 + kl) ^ ((n & 7) << 3)] = (short)f2bf(v);
    }
    __syncthreads();
    long base = dstbase + (long)s * K * 256 + (long)c * 16384;
    int4* dp = (int4*)(wdst + base);
    const int4* tp = (const int4*)Ts;
    #pragma unroll
    for (int i = 0; i < 8; ++i) dp[threadIdx.x + i * 256] = tp[threadIdx.x + i * 256];
}

// gW1[s][n] = sum_k gamma[k]*W1[s][k][n]; bW1 likewise with beta. Also zeroes d_out.
__global__ __launch_bounds__(256) void prep_gb(const float* __restrict__ Wps1,
                                               const float* __restrict__ Wmp1,
                                               const float* __restrict__ g_ps,
                                               const float* __restrict__ b_ps,
                                               const float* __restrict__ g_mp,
                                               const float* __restrict__ b_mp,
                                               float* __restrict__ gbdst,
                                               float* __restrict__ out) {
    int gid = blockIdx.x * 256 + threadIdx.x;   // 0..2047
    if (gid < N_MOL) out[gid] = 0.0f;
    int which = gid >> 10;          // 0: ps, 1: mp
    int s = (gid >> 8) & 3;
    int n = gid & 255;
    const float* W  = which ? Wmp1 : Wps1;
    const float* ga = which ? g_mp : g_ps;
    const float* be = which ? b_mp : b_ps;
    int K = which ? 256 : 512;
    const float* wp = W + (long)s * K * 256 + n;
    float gs = 0.0f, bs = 0.0f;
    for (int k = 0; k < K; ++k) {
        float w = wp[(long)k * 256];
        gs += ga[k] * w;
        bs += be[k] * w;
    }
    float* dst = gbdst + which * 2048;
    dst[s * 256 + n] = gs;
    dst[1024 + s * 256 + n] = bs;
}

// Fused: LayerNorm (via linear fixup) -> MLP(F->256 silu ->256 silu ->1) -> scatter-add to out[batch].
template <int F>
__global__ __launch_bounds__(512, 1) void mlp_kernel(
    const float* __restrict__ x, const float* __restrict__ gamma,
    const short* __restrict__ W1, const short* __restrict__ W2,
    const float* __restrict__ gW1, const float* __restrict__ bW1,
    const float* __restrict__ W3, const int* __restrict__ batch,
    float* __restrict__ out) {
    constexpr int BM = 128;
    constexpr int NCHUNK1 = F / 64;
    __shared__ short As[BM * 64];        // 16 KB, swizzled [row][k]
    __shared__ short Bs[256 * 64];       // 32 KB, swizzled [n][k]
    __shared__ short H1[BM * 256];       // 64 KB, swizzled [row][k]
    __shared__ float2 rowstats[BM];
    __shared__ float e_lds[BM];

    const int tid = threadIdx.x;
    const int lane = tid & 63;
    const int wid = tid >> 6;
    const int wm = (wid >> 2) * 64;      // wave M offset (0 or 64)
    const int wn = (wid & 3) * 64;       // wave N offset (0,64,128,192)
    const int lg = lane >> 4;            // k-group on A/B load, row-group on C
    const int ln = lane & 15;

    const int block0 = blockIdx.x * BM;
    const int species = block0 / ATOMS_PER_SPECIES;
    const long wbase = (long)species * F * 256;
    const long w2base = (long)species * 256 * 256;

    if (tid < BM) { rowstats[tid] = make_float2(0.0f, 0.0f); e_lds[tid] = 0.0f; }

    f32x4 acc[4][4];
    #pragma unroll
    for (int m = 0; m < 4; ++m)
        #pragma unroll
        for (int n = 0; n < 4; ++n) acc[m][n] = (f32x4){0.f, 0.f, 0.f, 0.f};

    const int ar = tid >> 2;   // staging row 0..127
    const int aj = tid & 3;    // staging k-quarter
    const float* xrow = x + (long)(block0 + ar) * F;

    // ---------- GEMM1: (x .* gamma) @ W1, fused LN stats ----------
    for (int c = 0; c < NCHUNK1; ++c) {
        __syncthreads();
        {   // stage A chunk [128][64] + accumulate row stats
            int k0 = c * 64;
            float s1 = 0.0f, s2 = 0.0f;
            #pragma unroll
            for (int i = 0; i < 4; ++i) {
                int k = aj * 16 + i * 4;
                float4 xv = *(const float4*)(xrow + k0 + k);
                float4 gv = *(const float4*)(gamma + k0 + k);
                s1 += xv.x + xv.y + xv.z + xv.w;
                s2 += xv.x * xv.x + xv.y * xv.y + xv.z * xv.z + xv.w * xv.w;
                unsigned int lo = (unsigned int)f2bf(xv.x * gv.x) | ((unsigned int)f2bf(xv.y * gv.y) << 16);
                unsigned int hi = (unsigned int)f2bf(xv.z * gv.z) | ((unsigned int)f2bf(xv.w * gv.w) << 16);
                int e = (ar * 64 + k) ^ ((ar & 7) << 3);
                *(int2*)&As[e] = make_int2((int)lo, (int)hi);
            }
            s1 += __shfl_xor(s1, 1); s1 += __shfl_xor(s1, 2);
            s2 += __shfl_xor(s2, 1); s2 += __shfl_xor(s2, 2);
            if (aj == 0) {
                float2 rs = rowstats[ar];
                rs.x += s1; rs.y += s2;
                rowstats[ar] = rs;
            }
        }
        {   // stage B chunk: linear copy of pre-swizzled global image
            const int4* src = (const int4*)(W1 + wbase + (long)c * 16384);
            int4* dst = (int4*)Bs;
            #pragma unroll
            for (int q = 0; q < 4; ++q) dst[tid + q * 512] = src[tid + q * 512];
        }
        __syncthreads();
        #pragma unroll
        for (int ks = 0; ks < 2; ++ks) {
            bf16x8 a[4], b[4];
            #pragma unroll
            for (int m = 0; m < 4; ++m) {
                int row = wm + m * 16 + ln;
                int e = (row * 64 + ks * 32 + lg * 8) ^ ((row & 7) << 3);
                a[m] = *(const bf16x8*)&As[e];
            }
            #pragma unroll
            for (int n = 0; n < 4; ++n) {
                int col = wn + n * 16 + ln;
                int e = (col * 64 + ks * 32 + lg * 8) ^ ((col & 7) << 3);
                b[n] = *(const bf16x8*)&Bs[e];
            }
            #pragma unroll
            for (int m = 0; m < 4; ++m)
                #pragma unroll
                for (int n = 0; n < 4; ++n)
                    acc[m][n] = __builtin_amdgcn_mfma_f32_16x16x32_bf16(a[m], b[n], acc[m][n], 0, 0, 0);
        }
    }

    // ---------- LN fixup + SiLU -> H1 (bf16, LDS) ----------
    float gw[4], bw[4], w3c[4];
    #pragma unroll
    for (int n = 0; n < 4; ++n) {
        int col = wn + n * 16 + ln;
        gw[n]  = gW1[species * 256 + col];
        bw[n]  = bW1[species * 256 + col];
        w3c[n] = W3[species * 256 + col];
    }
    const float invF = 1.0f / (float)F;
    #pragma unroll
    for (int m = 0; m < 4; ++m) {
        #pragma unroll
        for (int rr = 0; rr < 4; ++rr) {
            int row = wm + m * 16 + lg * 4 + rr;
            float2 rs = rowstats[row];
            float mu = rs.x * invF;
            float var = rs.y * invF - mu * mu;
            float rstd = rsqrtf(var + 1e-5f);
            float nmu = rstd * mu;
            #pragma unroll
            for (int n = 0; n < 4; ++n) {
                float v = rstd * acc[m][n][rr] - nmu * gw[n] + bw[n];
                float h = silu(v);
                int col = wn + n * 16 + ln;
                H1[(row * 256 + col) ^ ((row & 7) << 3)] = (short)f2bf(h);
            }
        }
    }
    __syncthreads();

    // ---------- GEMM2: H1 @ W2 ----------
    f32x4 acc2[4][4];
    #pragma unroll
    for (int m = 0; m < 4; ++m)
        #pragma unroll
        for (int n = 0; n < 4; ++n) acc2[m][n] = (f32x4){0.f, 0.f, 0.f, 0.f};

    for (int c = 0; c < 4; ++c) {
        if (c) __syncthreads();
        {
            const int4* src = (const int4*)(W2 + w2base + (long)c * 16384);
            int4* dst = (int4*)Bs;
            #pragma unroll
            for (int q = 0; q < 4; ++q) dst[tid + q * 512] = src[tid + q * 512];
        }
        __syncthreads();
        #pragma unroll
        for (int ks = 0; ks < 2; ++ks) {
            bf16x8 a[4], b[4];
            #pragma unroll
            for (int m = 0; m < 4; ++m) {
                int row = wm + m * 16 + ln;
                int e = (row * 256 + c * 64 + ks * 32 + lg * 8) ^ ((row & 7) << 3);
                a[m] = *(const bf16x8*)&H1[e];
            }
            #pragma unroll
            for (int n = 0; n < 4; ++n) {
                int col = wn + n * 16 + ln;
                int e = (col * 64 + ks * 32 + lg * 8) ^ ((col & 7) << 3);
                b[n] = *(const bf16x8*)&Bs[e];
            }
            #pragma unroll
            for (int m = 0; m < 4; ++m)
                #pragma unroll
                for (int n = 0; n < 4; ++n)
                    acc2[m][n] = __builtin_amdgcn_mfma_f32_16x16x32_bf16(a[m], b[n], acc2[m][n], 0, 0, 0);
        }
    }

    // ---------- SiLU + dot W3 + scatter ----------
    #pragma unroll
    for (int m = 0; m < 4; ++m) {
        #pragma unroll
        for (int rr = 0; rr < 4; ++rr) {
            float p = 0.0f;
            #pragma unroll
            for (int n = 0; n < 4; ++n) {
                float v = acc2[m][n][rr];
                p += silu(v) * w3c[n];
            }
            p += __shfl_xor(p, 1); p += __shfl_xor(p, 2);
            p += __shfl_xor(p, 4); p += __shfl_xor(p, 8);
            if (ln == 0) atomicAdd(&e_lds[wm + m * 16 + lg * 4 + rr], p);
        }
    }
    __syncthreads();
    if (tid < BM) {
        int mol = batch[block0 + tid];
        atomicAdd(out + mol, e_lds[tid]);
    }
}

extern "C" void kernel_launch(void* const* d_in, const int* in_sizes, int n_in,
                              void* d_out, int out_size, void* d_ws, size_t ws_size,
                              hipStream_t stream) {
    const float* x_ps     = (const float*)d_in[0];
    const float* x_mp     = (const float*)d_in[1];
    const int*   batch    = (const int*)d_in[2];
    const float* gamma_ps = (const float*)d_in[3];
    const float* beta_ps  = (const float*)d_in[4];
    const float* gamma_mp = (const float*)d_in[5];
    const float* beta_mp  = (const float*)d_in[6];
    const float* W_ps1    = (const float*)d_in[7];
    const float* W_ps2    = (const float*)d_in[8];
    const float* W_ps3    = (const float*)d_in[9];
    const float* W_mp1    = (const float*)d_in[10];
    const float* W_mp2    = (const float*)d_in[11];
    const float* W_mp3    = (const float*)d_in[12];

    float* out = (float*)d_out;
    short* wsW = (short*)d_ws;
    float* gb  = (float*)((char*)d_ws + WS_GB_BYTES);

    hipLaunchKernelGGL(prep_w, dim3(80), dim3(256), 0, stream,
                       W_ps1, W_ps2, W_mp1, W_mp2, wsW);
    hipLaunchKernelGGL(prep_gb, dim3(8), dim3(256), 0, stream,
                       W_ps1, W_mp1, gamma_ps, beta_ps, gamma_mp, beta_mp, gb, out);

    hipLaunchKernelGGL((mlp_kernel<512>), dim3(N_ATOMS / 128), dim3(512), 0, stream,
                       x_ps, gamma_ps, wsW + WS_W1PS, wsW + WS_W2PS,
                       gb + 0, gb + 1024, W_ps3, batch, out);
    hipLaunchKernelGGL((mlp_kernel<256>), dim3(N_ATOMS / 128), dim3(512), 0, stream,
                       x_mp, gamma_mp, wsW + WS_W1MP, wsW + WS_W2MP,
                       gb + 2048, gb + 3072, W_mp3, batch, out);
}

// Round 2
// 180.503 us; speedup vs baseline: 1.5780x; 1.5780x over previous
//
#include <hip/hip_runtime.h>

#define N_ATOMS 65536
#define N_SPECIES 4
#define N_MOL 512
#define ATOMS_PER_SPECIES (N_ATOMS / N_SPECIES)

typedef __attribute__((ext_vector_type(8))) __bf16 bf16x8;
typedef __attribute__((ext_vector_type(4))) float f32x4;

__device__ __forceinline__ unsigned short f2bf(float f) {
    unsigned int u = __float_as_uint(f);
    unsigned int r = (u + 0x7fffu + ((u >> 16) & 1u)) >> 16;
    return (unsigned short)r;
}

__device__ __forceinline__ float silu(float v) {
    return v / (1.0f + __expf(-v));
}

// ws layout (shorts): W1ps[4*512*256] | W2ps[4*256*256] | W1mp[4*256*256] | W2mp[4*256*256]
// then (floats, at byte 2621440): gW1ps[1024] bW1ps[1024] gW1mp[1024] bW1mp[1024]
#define WS_W1PS 0
#define WS_W2PS 524288
#define WS_W1MP 786432
#define WS_W2MP 1048576
#define WS_GB_BYTES 2621440

// Transpose + bf16-convert + XOR-swizzle weights into ws.
// Chunk image: [256 n][64 k] bf16, elem = (n*64+kl) ^ ((n&7)<<3)  (matches LDS read swizzle)
// For W1 chunks, also accumulate gW1[s][n] = sum_k gamma[k]*W1[s][k][n] (and beta) via atomics.
__global__ __launch_bounds__(256) void prep_w(const float* __restrict__ Wps1,
                                              const float* __restrict__ Wps2,
                                              const float* __restrict__ Wmp1,
                                              const float* __restrict__ Wmp2,
                                              const float* __restrict__ g_ps,
                                              const float* __restrict__ b_ps,
                                              const float* __restrict__ g_mp,
                                              const float* __restrict__ b_mp,
                                              short* __restrict__ wdst,
                                              float* __restrict__ gb) {
    __shared__ short Ts[16384];
    int b = blockIdx.x;
    const float* src; int K; long dstbase; int s, c;
    const float* ga = nullptr; const float* be = nullptr; float* gbd = nullptr;
    if (b < 32)      { src = Wps1; K = 512; s = b >> 3;        c = b & 7;        dstbase = WS_W1PS;
                       ga = g_ps; be = b_ps; gbd = gb; }
    else if (b < 48) { src = Wps2; K = 256; s = (b - 32) >> 2; c = (b - 32) & 3; dstbase = WS_W2PS; }
    else if (b < 64) { src = Wmp1; K = 256; s = (b - 48) >> 2; c = (b - 48) & 3; dstbase = WS_W1MP;
                       ga = g_mp; be = b_mp; gbd = gb + 2048; }
    else             { src = Wmp2; K = 256; s = (b - 64) >> 2; c = (b - 64) & 3; dstbase = WS_W2MP; }
    int n = threadIdx.x;   // 0..255
    int k0 = c * 64;
    const float* sp = src + (long)s * K * 256 + (long)k0 * 256 + n;
    float gs = 0.0f, bs = 0.0f;
    if (gbd) {
        #pragma unroll 4
        for (int kl = 0; kl < 64; ++kl) {
            float v = sp[(long)kl * 256];
            gs += ga[k0 + kl] * v;
            bs += be[k0 + kl] * v;
            Ts[(n * 64 + kl) ^ ((n & 7) << 3)] = (short)f2bf(v);
        }
        atomicAdd(&gbd[s * 256 + n], gs);
        atomicAdd(&gbd[1024 + s * 256 + n], bs);
    } else {
        #pragma unroll 4
        for (int kl = 0; kl < 64; ++kl) {
            float v = sp[(long)kl * 256];
            Ts[(n * 64 + kl) ^ ((n & 7) << 3)] = (short)f2bf(v);
        }
    }
    __syncthreads();
    long base = dstbase + (long)s * K * 256 + (long)c * 16384;
    int4* dp = (int4*)(wdst + base);
    const int4* tp = (const int4*)Ts;
    #pragma unroll
    for (int i = 0; i < 8; ++i) dp[threadIdx.x + i * 256] = tp[threadIdx.x + i * 256];
}

// Fused: LayerNorm (via linear fixup) -> MLP(F->256 silu ->256 silu ->1) -> scatter-add to out[batch].
template <int F>
__global__ __launch_bounds__(512, 1) void mlp_kernel(
    const float* __restrict__ x, const float* __restrict__ gamma,
    const short* __restrict__ W1, const short* __restrict__ W2,
    const float* __restrict__ gW1, const float* __restrict__ bW1,
    const float* __restrict__ W3, const int* __restrict__ batch,
    float* __restrict__ out) {
    constexpr int BM = 128;
    constexpr int NCHUNK1 = F / 64;
    __shared__ short As[BM * 64];        // 16 KB, swizzled [row][k]
    __shared__ short Bs[256 * 64];       // 32 KB, swizzled [n][k]
    __shared__ short H1[BM * 256];       // 64 KB, swizzled [row][k]
    __shared__ float2 rowstats[BM];
    __shared__ float e_lds[BM];

    const int tid = threadIdx.x;
    const int lane = tid & 63;
    const int wid = tid >> 6;
    const int wm = (wid >> 2) * 64;      // wave M offset (0 or 64)
    const int wn = (wid & 3) * 64;       // wave N offset (0,64,128,192)
    const int lg = lane >> 4;            // k-group on A/B load, row-group on C
    const int ln = lane & 15;

    const int block0 = blockIdx.x * BM;
    const int species = block0 / ATOMS_PER_SPECIES;
    const long wbase = (long)species * F * 256;
    const long w2base = (long)species * 256 * 256;

    if (tid < BM) { rowstats[tid] = make_float2(0.0f, 0.0f); e_lds[tid] = 0.0f; }

    f32x4 acc[4][4];
    #pragma unroll
    for (int m = 0; m < 4; ++m)
        #pragma unroll
        for (int n = 0; n < 4; ++n) acc[m][n] = (f32x4){0.f, 0.f, 0.f, 0.f};

    const int ar = tid >> 2;   // staging row 0..127
    const int aj = tid & 3;    // staging k-quarter
    const float* xrow = x + (long)(block0 + ar) * F;

    // ---------- GEMM1: (x .* gamma) @ W1, fused LN stats ----------
    for (int c = 0; c < NCHUNK1; ++c) {
        __syncthreads();
        {   // stage A chunk [128][64] + accumulate row stats
            int k0 = c * 64;
            float s1 = 0.0f, s2 = 0.0f;
            #pragma unroll
            for (int i = 0; i < 4; ++i) {
                int k = aj * 16 + i * 4;
                float4 xv = *(const float4*)(xrow + k0 + k);
                float4 gv = *(const float4*)(gamma + k0 + k);
                s1 += xv.x + xv.y + xv.z + xv.w;
                s2 += xv.x * xv.x + xv.y * xv.y + xv.z * xv.z + xv.w * xv.w;
                unsigned int lo = (unsigned int)f2bf(xv.x * gv.x) | ((unsigned int)f2bf(xv.y * gv.y) << 16);
                unsigned int hi = (unsigned int)f2bf(xv.z * gv.z) | ((unsigned int)f2bf(xv.w * gv.w) << 16);
                int e = (ar * 64 + k) ^ ((ar & 7) << 3);
                *(int2*)&As[e] = make_int2((int)lo, (int)hi);
            }
            s1 += __shfl_xor(s1, 1); s1 += __shfl_xor(s1, 2);
            s2 += __shfl_xor(s2, 1); s2 += __shfl_xor(s2, 2);
            if (aj == 0) {
                float2 rs = rowstats[ar];
                rs.x += s1; rs.y += s2;
                rowstats[ar] = rs;
            }
        }
        {   // stage B chunk: linear copy of pre-swizzled global image
            const int4* src = (const int4*)(W1 + wbase + (long)c * 16384);
            int4* dst = (int4*)Bs;
            #pragma unroll
            for (int q = 0; q < 4; ++q) dst[tid + q * 512] = src[tid + q * 512];
        }
        __syncthreads();
        #pragma unroll
        for (int ks = 0; ks < 2; ++ks) {
            bf16x8 a[4], b[4];
            #pragma unroll
            for (int m = 0; m < 4; ++m) {
                int row = wm + m * 16 + ln;
                int e = (row * 64 + ks * 32 + lg * 8) ^ ((row & 7) << 3);
                a[m] = *(const bf16x8*)&As[e];
            }
            #pragma unroll
            for (int n = 0; n < 4; ++n) {
                int col = wn + n * 16 + ln;
                int e = (col * 64 + ks * 32 + lg * 8) ^ ((col & 7) << 3);
                b[n] = *(const bf16x8*)&Bs[e];
            }
            #pragma unroll
            for (int m = 0; m < 4; ++m)
                #pragma unroll
                for (int n = 0; n < 4; ++n)
                    acc[m][n] = __builtin_amdgcn_mfma_f32_16x16x32_bf16(a[m], b[n], acc[m][n], 0, 0, 0);
        }
    }

    // ---------- LN fixup + SiLU -> H1 (bf16, LDS) ----------
    float gw[4], bw[4], w3c[4];
    #pragma unroll
    for (int n = 0; n < 4; ++n) {
        int col = wn + n * 16 + ln;
        gw[n]  = gW1[species * 256 + col];
        bw[n]  = bW1[species * 256 + col];
        w3c[n] = W3[species * 256 + col];
    }
    const float invF = 1.0f / (float)F;
    #pragma unroll
    for (int m = 0; m < 4; ++m) {
        #pragma unroll
        for (int rr = 0; rr < 4; ++rr) {
            int row = wm + m * 16 + lg * 4 + rr;
            float2 rs = rowstats[row];
            float mu = rs.x * invF;
            float var = rs.y * invF - mu * mu;
            float rstd = rsqrtf(var + 1e-5f);
            float nmu = rstd * mu;
            #pragma unroll
            for (int n = 0; n < 4; ++n) {
                float v = rstd * acc[m][n][rr] - nmu * gw[n] + bw[n];
                float h = silu(v);
                int col = wn + n * 16 + ln;
                H1[(row * 256 + col) ^ ((row & 7) << 3)] = (short)f2bf(h);
            }
        }
    }
    __syncthreads();

    // ---------- GEMM2: H1 @ W2 ----------
    f32x4 acc2[4][4];
    #pragma unroll
    for (int m = 0; m < 4; ++m)
        #pragma unroll
        for (int n = 0; n < 4; ++n) acc2[m][n] = (f32x4){0.f, 0.f, 0.f, 0.f};

    for (int c = 0; c < 4; ++c) {
        if (c) __syncthreads();
        {
            const int4* src = (const int4*)(W2 + w2base + (long)c * 16384);
            int4* dst = (int4*)Bs;
            #pragma unroll
            for (int q = 0; q < 4; ++q) dst[tid + q * 512] = src[tid + q * 512];
        }
        __syncthreads();
        #pragma unroll
        for (int ks = 0; ks < 2; ++ks) {
            bf16x8 a[4], b[4];
            #pragma unroll
            for (int m = 0; m < 4; ++m) {
                int row = wm + m * 16 + ln;
                int e = (row * 256 + c * 64 + ks * 32 + lg * 8) ^ ((row & 7) << 3);
                a[m] = *(const bf16x8*)&H1[e];
            }
            #pragma unroll
            for (int n = 0; n < 4; ++n) {
                int col = wn + n * 16 + ln;
                int e = (col * 64 + ks * 32 + lg * 8) ^ ((col & 7) << 3);
                b[n] = *(const bf16x8*)&Bs[e];
            }
            #pragma unroll
            for (int m = 0; m < 4; ++m)
                #pragma unroll
                for (int n = 0; n < 4; ++n)
                    acc2[m][n] = __builtin_amdgcn_mfma_f32_16x16x32_bf16(a[m], b[n], acc2[m][n], 0, 0, 0);
        }
    }

    // ---------- SiLU + dot W3 + scatter ----------
    #pragma unroll
    for (int m = 0; m < 4; ++m) {
        #pragma unroll
        for (int rr = 0; rr < 4; ++rr) {
            float p = 0.0f;
            #pragma unroll
            for (int n = 0; n < 4; ++n) {
                float v = acc2[m][n][rr];
                p += silu(v) * w3c[n];
            }
            p += __shfl_xor(p, 1); p += __shfl_xor(p, 2);
            p += __shfl_xor(p, 4); p += __shfl_xor(p, 8);
            if (ln == 0) atomicAdd(&e_lds[wm + m * 16 + lg * 4 + rr], p);
        }
    }
    __syncthreads();
    if (tid < BM) {
        int mol = batch[block0 + tid];
        atomicAdd(out + mol, e_lds[tid]);
    }
}

extern "C" void kernel_launch(void* const* d_in, const int* in_sizes, int n_in,
                              void* d_out, int out_size, void* d_ws, size_t ws_size,
                              hipStream_t stream) {
    const float* x_ps     = (const float*)d_in[0];
    const float* x_mp     = (const float*)d_in[1];
    const int*   batch    = (const int*)d_in[2];
    const float* gamma_ps = (const float*)d_in[3];
    const float* beta_ps  = (const float*)d_in[4];
    const float* gamma_mp = (const float*)d_in[5];
    const float* beta_mp  = (const float*)d_in[6];
    const float* W_ps1    = (const float*)d_in[7];
    const float* W_ps2    = (const float*)d_in[8];
    const float* W_ps3    = (const float*)d_in[9];
    const float* W_mp1    = (const float*)d_in[10];
    const float* W_mp2    = (const float*)d_in[11];
    const float* W_mp3    = (const float*)d_in[12];

    float* out = (float*)d_out;
    short* wsW = (short*)d_ws;
    float* gb  = (float*)((char*)d_ws + WS_GB_BYTES);

    // zero accumulator targets (graph-capture-legal)
    hipMemsetAsync(out, 0, N_MOL * sizeof(float), stream);
    hipMemsetAsync(gb, 0, 4096 * sizeof(float), stream);

    hipLaunchKernelGGL(prep_w, dim3(80), dim3(256), 0, stream,
                       W_ps1, W_ps2, W_mp1, W_mp2,
                       gamma_ps, beta_ps, gamma_mp, beta_mp, wsW, gb);

    hipLaunchKernelGGL((mlp_kernel<512>), dim3(N_ATOMS / 128), dim3(512), 0, stream,
                       x_ps, gamma_ps, wsW + WS_W1PS, wsW + WS_W2PS,
                       gb + 0, gb + 1024, W_ps3, batch, out);
    hipLaunchKernelGGL((mlp_kernel<256>), dim3(N_ATOMS / 128), dim3(512), 0, stream,
                       x_mp, gamma_mp, wsW + WS_W1MP, wsW + WS_W2MP,
                       gb + 2048, gb + 3072, W_mp3, batch, out);
}

// Round 3
// 147.616 us; speedup vs baseline: 1.9296x; 1.2228x over previous
//
#include <hip/hip_runtime.h>

#define N_ATOMS 65536
#define N_MOL 512

typedef __attribute__((ext_vector_type(8))) __bf16 bf16x8;
typedef __attribute__((ext_vector_type(4))) float f32x4;

__device__ __forceinline__ unsigned int f2bf(float f) {
    unsigned int u = __float_as_uint(f);
    return (u + 0x7fffu + ((u >> 16) & 1u)) >> 16;
}

__device__ __forceinline__ int pack2(float a, float b) {
    return (int)(f2bf(a) | (f2bf(b) << 16));
}

__device__ __forceinline__ float silu(float v) {
    return v / (1.0f + __expf(-v));
}

// async global->LDS, 16B per lane, linear dest (wave-uniform base + lane*16)
#define GLDS16(gp, lp)                                                        \
    __builtin_amdgcn_global_load_lds(                                         \
        (__attribute__((address_space(1))) void*)(uintptr_t)(gp),             \
        (__attribute__((address_space(3))) void*)(uintptr_t)(lp), 16, 0, 0)

// ws layout (shorts): W1ps'[4*512*256] | W2ps[4*256*256] | W1mp'[4*256*256] | W2mp[4*256*256]
// (W1' = gamma-folded). Then floats at byte 2621440: gW1ps[1024] bW1ps[1024] gW1mp[1024] bW1mp[1024]
#define WS_W1PS 0
#define WS_W2PS 524288
#define WS_W1MP 786432
#define WS_W2MP 1048576
#define WS_GB_BYTES 2621440

// Weight prep: transpose, bf16-convert, gamma-fold (W1), swizzle into 32-k chunk images.
// Chunk image: [256 n][32 k] bf16; 16B-block index i16 = n*4 + ((k>>3) ^ ((n>>1)&3)).
// Also gW1[s][n] = sum_k bf16(gamma[k]*W1[s][k][n]) and bW1[s][n] = sum_k beta[k]*W1[s][k][n].
__global__ __launch_bounds__(256) void prep_w(const float* __restrict__ Wps1,
                                              const float* __restrict__ Wps2,
                                              const float* __restrict__ Wmp1,
                                              const float* __restrict__ Wmp2,
                                              const float* __restrict__ g_ps,
                                              const float* __restrict__ b_ps,
                                              const float* __restrict__ g_mp,
                                              const float* __restrict__ b_mp,
                                              short* __restrict__ wdst,
                                              float* __restrict__ gb) {
    __shared__ short Ts[16384];
    int b = blockIdx.x;
    const float* src; int K; long dstbase; int s, c;
    const float* ga = nullptr; const float* be = nullptr; float* gbd = nullptr;
    if (b < 32)      { src = Wps1; K = 512; s = b >> 3;        c = b & 7;        dstbase = WS_W1PS;
                       ga = g_ps; be = b_ps; gbd = gb; }
    else if (b < 48) { src = Wps2; K = 256; s = (b - 32) >> 2; c = (b - 32) & 3; dstbase = WS_W2PS; }
    else if (b < 64) { src = Wmp1; K = 256; s = (b - 48) >> 2; c = (b - 48) & 3; dstbase = WS_W1MP;
                       ga = g_mp; be = b_mp; gbd = gb + 2048; }
    else             { src = Wmp2; K = 256; s = (b - 64) >> 2; c = (b - 64) & 3; dstbase = WS_W2MP; }
    int n = threadIdx.x;   // output column 0..255
    int k0 = c * 64;
    const float* sp = src + (long)s * K * 256 + (long)k0 * 256 + n;
    if (ga) {
        float gs = 0.0f, bs = 0.0f;
        #pragma unroll 4
        for (int kl = 0; kl < 64; ++kl) {
            float v = sp[(long)kl * 256];
            unsigned int h = f2bf(v * ga[k0 + kl]);
            gs += __uint_as_float(h << 16);
            bs += be[k0 + kl] * v;
            int klc = kl & 31, ch = kl >> 5;
            int i16 = n * 4 + ((klc >> 3) ^ ((n >> 1) & 3));
            Ts[ch * 8192 + i16 * 8 + (klc & 7)] = (short)h;
        }
        atomicAdd(&gbd[s * 256 + n], gs);
        atomicAdd(&gbd[1024 + s * 256 + n], bs);
    } else {
        #pragma unroll 4
        for (int kl = 0; kl < 64; ++kl) {
            unsigned int h = f2bf(sp[(long)kl * 256]);
            int klc = kl & 31, ch = kl >> 5;
            int i16 = n * 4 + ((klc >> 3) ^ ((n >> 1) & 3));
            Ts[ch * 8192 + i16 * 8 + (klc & 7)] = (short)h;
        }
    }
    __syncthreads();
    long base = dstbase + (long)s * K * 256 + (long)c * 16384;
    int4* dp = (int4*)(wdst + base);
    const int4* tp = (const int4*)Ts;
    #pragma unroll
    for (int i = 0; i < 8; ++i) dp[threadIdx.x + i * 256] = tp[threadIdx.x + i * 256];
}

// One fused kernel for both branches. Block = 64 atoms, 256 threads = 4 waves (1M x 4N),
// per-wave output 64x64. Blocks [0,1024): ps (F=512); [1024,2048): mp (F=256).
// LDS: As 4K + Bs 16K + H1 32K + stats ~0.75K = ~54K -> 3 blocks/CU.
__global__ __launch_bounds__(256, 3) void mlp_all(
    const float* __restrict__ x_ps, const float* __restrict__ x_mp,
    const short* __restrict__ wimg, const float* __restrict__ gb,
    const float* __restrict__ W3ps, const float* __restrict__ W3mp,
    const int* __restrict__ batch, float* __restrict__ out) {
    __shared__ short As[2048];       // [64 rows][32 k] bf16, swizzled
    __shared__ short Bs[8192];       // [256 cols][32 k] bf16, swizzled (pre-swizzled image)
    __shared__ short H1[16384];      // [64 rows][256 k] bf16, swizzled
    __shared__ float2 rowstats[64];
    __shared__ float e_lds[64];

    const int tid = threadIdx.x;
    const int lane = tid & 63;
    const int wid = tid >> 6;
    const int wn = wid * 64;         // wave column offset
    const int lg = lane >> 4;        // k-group / row-group
    const int ln = lane & 15;

    const bool mp = blockIdx.x >= 1024;
    const int tile = mp ? (int)blockIdx.x - 1024 : (int)blockIdx.x;
    const float* x = mp ? x_mp : x_ps;
    const int F = mp ? 256 : 512;
    const int nch1 = F >> 5;
    const int block0 = tile * 64;
    const int species = block0 >> 14;          // 16384 atoms per species
    const short* W1 = wimg + (mp ? WS_W1MP : WS_W1PS) + (size_t)species * F * 256;
    const short* W2 = wimg + (mp ? WS_W2MP : WS_W2PS) + (size_t)species * 65536;
    const float* gW1 = gb + (mp ? 2048 : 0) + species * 256;
    const float* bW1 = gW1 + 1024;
    const float* W3 = (mp ? W3mp : W3ps) + species * 256;

    if (tid < 64) e_lds[tid] = 0.0f;

    const int ar = tid >> 2;         // staging row 0..63
    const int aj = tid & 3;          // staging k-quarter (8 floats each)
    const float* xrow = x + (size_t)(block0 + ar) * F + aj * 8;

    f32x4 acc[4][4];
    #pragma unroll
    for (int m = 0; m < 4; ++m)
        #pragma unroll
        for (int n = 0; n < 4; ++n) acc[m][n] = (f32x4){0.f, 0.f, 0.f, 0.f};
    float s1 = 0.0f, s2 = 0.0f;

    // ---------- GEMM1: x @ W1' (gamma folded), LN stats in regs ----------
    for (int c = 0; c < nch1; ++c) {
        if (c) __syncthreads();
        {   // stage B chunk via async global->LDS (image pre-swizzled, linear copy)
            const int4* gsrc = (const int4*)(W1 + (size_t)c * 8192);
            int4* bsl = (int4*)Bs;
            #pragma unroll
            for (int q = 0; q < 4; ++q) {
                int idx = wid * 256 + q * 64;
                GLDS16(gsrc + idx + lane, bsl + idx);
            }
        }
        {   // stage A: 8 floats of x -> stats + bf16 pack -> swizzled LDS
            const float4 u = *(const float4*)(xrow + c * 32);
            const float4 v = *(const float4*)(xrow + c * 32 + 4);
            s1 += u.x + u.y + u.z + u.w + v.x + v.y + v.z + v.w;
            s2 += u.x * u.x + u.y * u.y + u.z * u.z + u.w * u.w
                + v.x * v.x + v.y * v.y + v.z * v.z + v.w * v.w;
            int4 p;
            p.x = pack2(u.x, u.y); p.y = pack2(u.z, u.w);
            p.z = pack2(v.x, v.y); p.w = pack2(v.z, v.w);
            int i16 = ar * 4 + (aj ^ ((ar >> 1) & 3));
            *(int4*)&As[i16 * 8] = p;
        }
        __syncthreads();
        bf16x8 a[4], b[4];
        #pragma unroll
        for (int m = 0; m < 4; ++m) {
            int row = m * 16 + ln;
            int i16 = row * 4 + (lg ^ ((row >> 1) & 3));
            a[m] = *(const bf16x8*)&As[i16 * 8];
        }
        #pragma unroll
        for (int n = 0; n < 4; ++n) {
            int col = wn + n * 16 + ln;
            int i16 = col * 4 + (lg ^ ((col >> 1) & 3));
            b[n] = *(const bf16x8*)&Bs[i16 * 8];
        }
        #pragma unroll
        for (int m = 0; m < 4; ++m)
            #pragma unroll
            for (int n = 0; n < 4; ++n)
                acc[m][n] = __builtin_amdgcn_mfma_f32_16x16x32_bf16(a[m], b[n], acc[m][n], 0, 0, 0);
    }

    // finalize LN stats (reduce the 4 k-quarter partials)
    s1 += __shfl_xor(s1, 1); s1 += __shfl_xor(s1, 2);
    s2 += __shfl_xor(s2, 1); s2 += __shfl_xor(s2, 2);
    if (aj == 0) rowstats[ar] = make_float2(s1, s2);
    __syncthreads();

    // ---------- LN fixup + SiLU -> H1 ----------
    float gwv[4], bwv[4], w3v[4];
    #pragma unroll
    for (int n = 0; n < 4; ++n) {
        int col = wn + n * 16 + ln;
        gwv[n] = gW1[col]; bwv[n] = bW1[col]; w3v[n] = W3[col];
    }
    const float invF = mp ? (1.0f / 256.0f) : (1.0f / 512.0f);
    #pragma unroll
    for (int m = 0; m < 4; ++m) {
        #pragma unroll
        for (int rr = 0; rr < 4; ++rr) {
            int row = m * 16 + lg * 4 + rr;
            float2 rs = rowstats[row];
            float mu = rs.x * invF;
            float var = rs.y * invF - mu * mu;
            float rstd = rsqrtf(var + 1e-5f);
            float nmu = rstd * mu;
            #pragma unroll
            for (int n = 0; n < 4; ++n) {
                float v = rstd * acc[m][n][rr] - nmu * gwv[n] + bwv[n];
                int col = wn + n * 16 + ln;
                H1[(row * 256 + col) ^ ((row & 7) << 3)] = (short)f2bf(silu(v));
            }
        }
    }

    // ---------- GEMM2: H1 @ W2 ----------
    f32x4 acc2[4][4];
    #pragma unroll
    for (int m = 0; m < 4; ++m)
        #pragma unroll
        for (int n = 0; n < 4; ++n) acc2[m][n] = (f32x4){0.f, 0.f, 0.f, 0.f};

    for (int c = 0; c < 8; ++c) {
        __syncthreads();   // c=0: H1 writes drained; c>0: Bs reads of c-1 done
        {
            const int4* gsrc = (const int4*)(W2 + (size_t)c * 8192);
            int4* bsl = (int4*)Bs;
            #pragma unroll
            for (int q = 0; q < 4; ++q) {
                int idx = wid * 256 + q * 64;
                GLDS16(gsrc + idx + lane, bsl + idx);
            }
        }
        __syncthreads();
        bf16x8 a[4], b[4];
        #pragma unroll
        for (int m = 0; m < 4; ++m) {
            int row = m * 16 + ln;
            int e = (row * 256 + c * 32 + lg * 8) ^ ((row & 7) << 3);
            a[m] = *(const bf16x8*)&H1[e];
        }
        #pragma unroll
        for (int n = 0; n < 4; ++n) {
            int col = wn + n * 16 + ln;
            int i16 = col * 4 + (lg ^ ((col >> 1) & 3));
            b[n] = *(const bf16x8*)&Bs[i16 * 8];
        }
        #pragma unroll
        for (int m = 0; m < 4; ++m)
            #pragma unroll
            for (int n = 0; n < 4; ++n)
                acc2[m][n] = __builtin_amdgcn_mfma_f32_16x16x32_bf16(a[m], b[n], acc2[m][n], 0, 0, 0);
    }

    // ---------- SiLU + dot W3 + scatter ----------
    #pragma unroll
    for (int m = 0; m < 4; ++m) {
        #pragma unroll
        for (int rr = 0; rr < 4; ++rr) {
            int row = m * 16 + lg * 4 + rr;
            float p = 0.0f;
            #pragma unroll
            for (int n = 0; n < 4; ++n) p += silu(acc2[m][n][rr]) * w3v[n];
            p += __shfl_xor(p, 1); p += __shfl_xor(p, 2);
            p += __shfl_xor(p, 4); p += __shfl_xor(p, 8);
            if (ln == 0) atomicAdd(&e_lds[row], p);
        }
    }
    __syncthreads();
    if (tid < 64) atomicAdd(out + batch[block0 + tid], e_lds[tid]);
}

extern "C" void kernel_launch(void* const* d_in, const int* in_sizes, int n_in,
                              void* d_out, int out_size, void* d_ws, size_t ws_size,
                              hipStream_t stream) {
    const float* x_ps     = (const float*)d_in[0];
    const float* x_mp     = (const float*)d_in[1];
    const int*   batch    = (const int*)d_in[2];
    const float* gamma_ps = (const float*)d_in[3];
    const float* beta_ps  = (const float*)d_in[4];
    const float* gamma_mp = (const float*)d_in[5];
    const float* beta_mp  = (const float*)d_in[6];
    const float* W_ps1    = (const float*)d_in[7];
    const float* W_ps2    = (const float*)d_in[8];
    const float* W_ps3    = (const float*)d_in[9];
    const float* W_mp1    = (const float*)d_in[10];
    const float* W_mp2    = (const float*)d_in[11];
    const float* W_mp3    = (const float*)d_in[12];

    float* out = (float*)d_out;
    short* wsW = (short*)d_ws;
    float* gb  = (float*)((char*)d_ws + WS_GB_BYTES);

    hipMemsetAsync(out, 0, N_MOL * sizeof(float), stream);
    hipMemsetAsync(gb, 0, 4096 * sizeof(float), stream);

    hipLaunchKernelGGL(prep_w, dim3(80), dim3(256), 0, stream,
                       W_ps1, W_ps2, W_mp1, W_mp2,
                       gamma_ps, beta_ps, gamma_mp, beta_mp, wsW, gb);

    hipLaunchKernelGGL(mlp_all, dim3(2048), dim3(256), 0, stream,
                       x_ps, x_mp, wsW, gb, W_ps3, W_mp3, batch, out);
}